// Round 10
// baseline (99.758 us; speedup 1.0000x reference)
//
#include <hip/hip_runtime.h>
#include <hip/hip_bf16.h>

typedef __attribute__((ext_vector_type(4))) short bf16x4;   // 4 bf16 = 2 VGPR
typedef __attribute__((ext_vector_type(4))) float f32x4;
typedef __attribute__((ext_vector_type(4))) int i32x4;

#define LOG2E 1.4426950408889634f
#define SMAX 8.0f   // fixed softmax shift (log2 domain); exact after normalization

static __device__ inline f32x4 mfma16(bf16x4 a, bf16x4 b, f32x4 c) {
  return __builtin_amdgcn_mfma_f32_16x16x16bf16_1k(a, b, c, 0, 0, 0);
}
static __device__ inline ushort f2bfu(float f) {
  __hip_bfloat16 h = __float2bfloat16(f);
  return *(ushort*)&h;
}
static __device__ __forceinline__ void dma16(const void* g, void* l) {
  __builtin_amdgcn_global_load_lds(
      (const __attribute__((address_space(1))) void*)g,
      (__attribute__((address_space(3))) void*)l, 16, 0, 0);
}

// ---------------------------------------------------------------------------
// Fused QKV projections, one launch. grid 3072 x 256; which = bid>>10.
// Q: row-major, scaled 0.25*log2e. K: per-head K^T16 Kt[((b8+h)*1024+n)*16+k].
// V: block-transposed Vt[((b8+h)*16+(n>>6))*1024 + d*64 + (n&63)].
// ---------------------------------------------------------------------------
__global__ __launch_bounds__(256) void gemm_qkv(
    const float* __restrict__ x,
    const float* __restrict__ Wq, const float* __restrict__ bq,
    const float* __restrict__ Wk, const float* __restrict__ bk,
    const float* __restrict__ Wv, const float* __restrict__ bv,
    ushort* __restrict__ Qs, ushort* __restrict__ Kt, ushort* __restrict__ Vt) {
  const int which = blockIdx.x >> 10;       // 0=Q 1=K 2=V
  const int bid = blockIdx.x & 1023;
  const int tid = threadIdx.x;
  const int l = tid & 63, w = tid >> 6;
  const int lm = l & 15, g = l >> 4;
  const int tile = bid * 4 + w;             // 0..4095
  const int mt = tile >> 3, nt = tile & 7;  // 512 x 8
  const int row = mt * 16 + lm;
  const int col = nt * 16 + lm;

  const float* W = (which == 0) ? Wq : (which == 1) ? Wk : Wv;
  const float* bias = (which == 0) ? bq : (which == 1) ? bk : bv;

  f32x4 acc = {0.f, 0.f, 0.f, 0.f};
#pragma unroll
  for (int ks = 0; ks < 8; ++ks) {
    f32x4 av = *(const f32x4*)(x + (size_t)row * 128 + ks * 16 + g * 4);
    bf16x4 a;
    a[0] = (short)f2bfu(av[0]); a[1] = (short)f2bfu(av[1]);
    a[2] = (short)f2bfu(av[2]); a[3] = (short)f2bfu(av[3]);
    const float* wp = W + (size_t)(ks * 16 + g * 4) * 128 + col;
    bf16x4 b;
    b[0] = (short)f2bfu(wp[0]);   b[1] = (short)f2bfu(wp[128]);
    b[2] = (short)f2bfu(wp[256]); b[3] = (short)f2bfu(wp[384]);
    acc = mfma16(a, b, acc);
  }
  const float bv_ = bias[col];
  const float alpha = (which == 0) ? 0.25f * LOG2E : 1.0f;
  float v0 = (acc[0] + bv_) * alpha, v1 = (acc[1] + bv_) * alpha;
  float v2 = (acc[2] + bv_) * alpha, v3 = (acc[3] + bv_) * alpha;
  const int mb = mt * 16;

  if (which == 0) {
    Qs[(size_t)(mb + g * 4 + 0) * 128 + col] = f2bfu(v0);
    Qs[(size_t)(mb + g * 4 + 1) * 128 + col] = f2bfu(v1);
    Qs[(size_t)(mb + g * 4 + 2) * 128 + col] = f2bfu(v2);
    Qs[(size_t)(mb + g * 4 + 3) * 128 + col] = f2bfu(v3);
  } else if (which == 1) {
    const size_t kb = ((size_t)((mb >> 10) * 8 + nt) * 1024 + ((mb & 1023) + g * 4));
    Kt[(kb + 0) * 16 + lm] = f2bfu(v0);
    Kt[(kb + 1) * 16 + lm] = f2bfu(v1);
    Kt[(kb + 2) * 16 + lm] = f2bfu(v2);
    Kt[(kb + 3) * 16 + lm] = f2bfu(v3);
  } else {
    const size_t addr = ((size_t)((mb >> 10) * 8 + nt) * 16 + ((mb & 1023) >> 6)) * 1024
                        + (size_t)lm * 64 + (mb & 63) + g * 4;
    bf16x4 vv;
    vv[0] = (short)f2bfu(v0); vv[1] = (short)f2bfu(v1);
    vv[2] = (short)f2bfu(v2); vv[3] = (short)f2bfu(v3);
    *(bf16x4*)(Vt + addr) = vv;
  }
}

// ---------------------------------------------------------------------------
// Fused attention + output projection. One WG = (b, 16-row m-tile); 8 waves
// = 8 heads. 16 tiles x 64 cols. adj/edge: 4-buffer DMA pipeline (8 KB/buf,
// depth 3, counted vmcnt targeting only DMAs). K/V: register loads with
// 1-iter prefetch (L2-resident). Fixed-shift log2 softmax. Epilogue: O-tile
// through LDS -> AO@Wo+bo -> f32 out (gemm_out folded in).
// ---------------------------------------------------------------------------
#define SBUF 8192   // per buffer: adj 4KB | edge 4KB

__global__ __launch_bounds__(512) void attn_kernel(
    const ushort* __restrict__ Qs, const ushort* __restrict__ Kt,
    const ushort* __restrict__ Vt, const int* __restrict__ adj,
    const float* __restrict__ edge, const float* __restrict__ We,
    const float* __restrict__ Wo, const float* __restrict__ bo,
    float* __restrict__ out) {
  __shared__ __align__(16) char smem[4 * SBUF];

  const int tid = threadIdx.x;
  const int l = tid & 63, h = tid >> 6;
  const int lm = l & 15, g = l >> 4;
  const int b = blockIdx.x >> 6;
  const int m0 = (blockIdx.x & 63) * 16;

  const float Weh = We[h] * LOG2E;
  // B-frag of S^T = K.Q^T : lane holds Q[m0+lm][k=4g+j] (0.25*log2e folded)
  const bf16x4 qf = *(const bf16x4*)(Qs + ((size_t)b * 1024 + m0 + lm) * 128 + h * 16 + g * 4);

  const ushort* kp = Kt + ((size_t)b * 8 + h) * 16384 + lm * 16 + g * 4;  // + T*1024
  const ushort* vp = Vt + ((size_t)b * 8 + h) * 16384 + lm * 64 + g * 4;  // + T*1024

  // staging: waves 0-3 adj, 4-7 edge; 1 DMA (1KB = 4 rows) per wave per tile
  const int sr = (h & 3) * 4 + (l >> 4);                // tile row 0..15
  const int sg = (l & 15) ^ (sr & 7);                   // src granule (16B, swz)
  const int* ssrc = ((h < 4) ? adj : (const int*)edge)
                    + (size_t)b * 1048576 + (size_t)(m0 + sr) * 1024 + sg * 4;
  char* sdst = smem + ((h < 4) ? 0 : 4096) + (h & 3) * 1024;

  // prologue: KV(0) regs first (oldest), then DMA tiles 0,1,2
  bf16x4 kfr[2][4], vfr[2][4];
#pragma unroll
  for (int t = 0; t < 4; ++t) {
    kfr[0][t] = *(const bf16x4*)(kp + t * 256);
    vfr[0][t] = *(const bf16x4*)(vp + t * 16);
  }
  __builtin_amdgcn_sched_barrier(0);
  dma16(ssrc,            sdst);
  dma16(ssrc + 1 * 64,   sdst + 1 * SBUF);
  dma16(ssrc + 2 * 64,   sdst + 2 * SBUF);

  float lsum = 0.f;
  f32x4 oacc = {0.f, 0.f, 0.f, 0.f};
  const f32x4 cinit = {-SMAX, -SMAX, -SMAX, -SMAX};

#pragma unroll
  for (int ct = 0; ct < 16; ++ct) {
    // manual wait: DMA(ct) landed; newer DMAs + KV stay in flight
    if (ct == 0)       asm volatile("s_waitcnt vmcnt(2)" ::: "memory");
    else if (ct <= 13) asm volatile("s_waitcnt vmcnt(10)" ::: "memory");
    else if (ct == 14) asm volatile("s_waitcnt vmcnt(9)" ::: "memory");
    else               asm volatile("s_waitcnt vmcnt(8)" ::: "memory");
    __builtin_amdgcn_s_barrier();
    __builtin_amdgcn_sched_barrier(0);

    // (1) KV register prefetch for tile ct+1 (oldest in this iter's issues)
    if (ct < 15) {
#pragma unroll
      for (int t = 0; t < 4; ++t) {
        kfr[(ct + 1) & 1][t] = *(const bf16x4*)(kp + (ct + 1) * 1024 + t * 256);
        vfr[(ct + 1) & 1][t] = *(const bf16x4*)(vp + (ct + 1) * 1024 + t * 16);
      }
    }
    __builtin_amdgcn_sched_barrier(0);
    // (2) DMA tile ct+3 into buffer (ct+3)&3 (vacated; race-free by barrier)
    if (ct < 13) dma16(ssrc + (ct + 3) * 64, sdst + ((ct + 3) & 3) * SBUF);
    __builtin_amdgcn_sched_barrier(0);

    // (3) compute tile ct from buffer ct&3 + kfr/vfr[ct&1]
    const char* base = smem + (ct & 3) * SBUF;
    const int* als = (const int*)base;
    const int* els = (const int*)(base + 4096);

    f32x4 st[4];
#pragma unroll
    for (int t = 0; t < 4; ++t) st[t] = mfma16(kfr[ct & 1][t], qf, cinit);

#pragma unroll
    for (int t = 0; t < 4; ++t) {
      const int gi = ((4 * t + g) ^ (lm & 7)) * 4;   // swizzled int offset
      const i32x4 a4 = *(const i32x4*)(als + lm * 64 + gi);
      const i32x4 e4i = *(const i32x4*)(els + lm * 64 + gi);
      const f32x4 e4 = *(const f32x4*)&e4i;
      bf16x4 pf4;
#pragma unroll
      for (int j = 0; j < 4; ++j) {
        float p = __builtin_amdgcn_exp2f(fmaf(e4[j], Weh, st[t][j]));
        p = (a4[j] == 0) ? 0.f : p;
        lsum += p;
        pf4[j] = (short)f2bfu(p);
      }
      // P^T (S^T C/D layout) == B-frag of PV; O^T[d=4g+r][m=lm]
      oacc = mfma16(vfr[ct & 1][t], pf4, oacc);
    }
  }

  // ---- epilogue: normalize, AO tile -> LDS, out = AO @ Wo + bo ----
  lsum += __shfl_xor(lsum, 16, 64);
  lsum += __shfl_xor(lsum, 32, 64);
  const float inv = 1.0f / lsum;

  ushort* aot = (ushort*)smem;   // 16 x 132 bf16 (aliases buf0; safe: see r10 notes)
  {
    bf16x4 ov;
    ov[0] = (short)f2bfu(oacc[0] * inv);
    ov[1] = (short)f2bfu(oacc[1] * inv);
    ov[2] = (short)f2bfu(oacc[2] * inv);
    ov[3] = (short)f2bfu(oacc[3] * inv);
    *(bf16x4*)(aot + lm * 132 + h * 16 + g * 4) = ov;   // AO[m=lm][h*16+4g+r]
  }
  __syncthreads();

  f32x4 acc = {0.f, 0.f, 0.f, 0.f};
#pragma unroll
  for (int ks = 0; ks < 8; ++ks) {
    bf16x4 a = *(const bf16x4*)(aot + lm * 132 + ks * 16 + g * 4);  // AO[lm][k]
    const float* wp = Wo + (size_t)(ks * 16 + g * 4) * 128 + h * 16 + lm;
    bf16x4 bfr;
    bfr[0] = (short)f2bfu(wp[0]);   bfr[1] = (short)f2bfu(wp[128]);
    bfr[2] = (short)f2bfu(wp[256]); bfr[3] = (short)f2bfu(wp[384]);
    acc = mfma16(a, bfr, acc);
  }
  const float bv = bo[h * 16 + lm];
  float* op = out + ((size_t)b * 1024 + m0 + g * 4) * 128 + h * 16 + lm;
  op[0 * 128] = acc[0] + bv;
  op[1 * 128] = acc[1] + bv;
  op[2 * 128] = acc[2] + bv;
  op[3 * 128] = acc[3] + bv;
}

extern "C" void kernel_launch(void* const* d_in, const int* in_sizes, int n_in,
                              void* d_out, int out_size, void* d_ws, size_t ws_size,
                              hipStream_t stream) {
  const float* x   = (const float*)d_in[0];
  const int*   adj = (const int*)d_in[1];
  const float* ew  = (const float*)d_in[2];
  const float* Wq  = (const float*)d_in[3];
  const float* bq  = (const float*)d_in[4];
  const float* Wk  = (const float*)d_in[5];
  const float* bk  = (const float*)d_in[6];
  const float* Wv  = (const float*)d_in[7];
  const float* bv  = (const float*)d_in[8];
  const float* Wo  = (const float*)d_in[9];
  const float* bo  = (const float*)d_in[10];
  const float* We  = (const float*)d_in[11];
  // be (d_in[12]) dropped: softmax(x + c) == softmax(x)

  const size_t MN = (size_t)8 * 1024 * 128;  // 1M elements
  ushort* Qs = (ushort*)d_ws;
  ushort* Kt = Qs + MN;
  ushort* Vt = Kt + MN;

  gemm_qkv<<<3072, 256, 0, stream>>>(x, Wq, bq, Wk, bk, Wv, bv, Qs, Kt, Vt);
  attn_kernel<<<512, 512, 0, stream>>>(Qs, Kt, Vt, adj, ew, We, Wo, bo, (float*)d_out);
}

// Round 13
// 61.165 us; speedup vs baseline: 1.6310x; 1.6310x over previous
//
#include <hip/hip_runtime.h>
#include <hip/hip_bf16.h>

typedef __attribute__((ext_vector_type(4))) short bf16x4;   // 4 bf16 = 2 VGPR
typedef __attribute__((ext_vector_type(4))) float f32x4;
typedef __attribute__((ext_vector_type(4))) int i32x4;

#define LOG2E 1.4426950408889634f
#define SMAX 8.0f   // fixed softmax shift (log2 domain); exact after normalization

static __device__ inline f32x4 mfma16(bf16x4 a, bf16x4 b, f32x4 c) {
  return __builtin_amdgcn_mfma_f32_16x16x16bf16_1k(a, b, c, 0, 0, 0);
}
static __device__ inline ushort f2bfu(float f) {
  __hip_bfloat16 h = __float2bfloat16(f);
  return *(ushort*)&h;
}
static __device__ __forceinline__ void dma16(const void* g, void* l) {
  __builtin_amdgcn_global_load_lds(
      (const __attribute__((address_space(1))) void*)g,
      (__attribute__((address_space(3))) void*)l, 16, 0, 0);
}

// ---------------------------------------------------------------------------
// Fused QKV projections, one launch (r10-verified). grid 3072 x 256.
// Q: row-major, scaled 0.25*log2e. K: per-head K^T16 Kt[((b8+h)*1024+n)*16+k].
// V: block-transposed Vt[((b8+h)*16+(n>>6))*1024 + d*64 + (n&63)].
// ---------------------------------------------------------------------------
__global__ __launch_bounds__(256) void gemm_qkv(
    const float* __restrict__ x,
    const float* __restrict__ Wq, const float* __restrict__ bq,
    const float* __restrict__ Wk, const float* __restrict__ bk,
    const float* __restrict__ Wv, const float* __restrict__ bv,
    ushort* __restrict__ Qs, ushort* __restrict__ Kt, ushort* __restrict__ Vt) {
  const int which = blockIdx.x >> 10;       // 0=Q 1=K 2=V
  const int bid = blockIdx.x & 1023;
  const int tid = threadIdx.x;
  const int l = tid & 63, w = tid >> 6;
  const int lm = l & 15, g = l >> 4;
  const int tile = bid * 4 + w;             // 0..4095
  const int mt = tile >> 3, nt = tile & 7;  // 512 x 8
  const int row = mt * 16 + lm;
  const int col = nt * 16 + lm;

  const float* W = (which == 0) ? Wq : (which == 1) ? Wk : Wv;
  const float* bias = (which == 0) ? bq : (which == 1) ? bk : bv;

  f32x4 acc = {0.f, 0.f, 0.f, 0.f};
#pragma unroll
  for (int ks = 0; ks < 8; ++ks) {
    f32x4 av = *(const f32x4*)(x + (size_t)row * 128 + ks * 16 + g * 4);
    bf16x4 a;
    a[0] = (short)f2bfu(av[0]); a[1] = (short)f2bfu(av[1]);
    a[2] = (short)f2bfu(av[2]); a[3] = (short)f2bfu(av[3]);
    const float* wp = W + (size_t)(ks * 16 + g * 4) * 128 + col;
    bf16x4 b;
    b[0] = (short)f2bfu(wp[0]);   b[1] = (short)f2bfu(wp[128]);
    b[2] = (short)f2bfu(wp[256]); b[3] = (short)f2bfu(wp[384]);
    acc = mfma16(a, b, acc);
  }
  const float bv_ = bias[col];
  const float alpha = (which == 0) ? 0.25f * LOG2E : 1.0f;
  float v0 = (acc[0] + bv_) * alpha, v1 = (acc[1] + bv_) * alpha;
  float v2 = (acc[2] + bv_) * alpha, v3 = (acc[3] + bv_) * alpha;
  const int mb = mt * 16;

  if (which == 0) {
    Qs[(size_t)(mb + g * 4 + 0) * 128 + col] = f2bfu(v0);
    Qs[(size_t)(mb + g * 4 + 1) * 128 + col] = f2bfu(v1);
    Qs[(size_t)(mb + g * 4 + 2) * 128 + col] = f2bfu(v2);
    Qs[(size_t)(mb + g * 4 + 3) * 128 + col] = f2bfu(v3);
  } else if (which == 1) {
    const size_t kb = ((size_t)((mb >> 10) * 8 + nt) * 1024 + ((mb & 1023) + g * 4));
    Kt[(kb + 0) * 16 + lm] = f2bfu(v0);
    Kt[(kb + 1) * 16 + lm] = f2bfu(v1);
    Kt[(kb + 2) * 16 + lm] = f2bfu(v2);
    Kt[(kb + 3) * 16 + lm] = f2bfu(v3);
  } else {
    const size_t addr = ((size_t)((mb >> 10) * 8 + nt) * 16 + ((mb & 1023) >> 6)) * 1024
                        + (size_t)lm * 64 + (mb & 63) + g * 4;
    bf16x4 vv;
    vv[0] = (short)f2bfu(v0); vv[1] = (short)f2bfu(v1);
    vv[2] = (short)f2bfu(v2); vv[3] = (short)f2bfu(v3);
    *(bf16x4*)(Vt + addr) = vv;
  }
}

// ---------------------------------------------------------------------------
// Fused attention (r9-verified all-DMA pipeline, EXACT swizzle pair restored)
// + output projection (r10-verified epilogue). One WG = (b, 16-row m-tile);
// 8 waves = 8 heads. 16 tiles x 64 cols; 5 DMAs/wave/tile; counted vmcnt(5);
// 3 buffers x 40 KB.
// ---------------------------------------------------------------------------
#define BUFB 40960  // bytes per LDS buffer: K 16K | V 16K | adj 4K | edge 4K

__global__ __launch_bounds__(512) void attn_kernel(
    const ushort* __restrict__ Qs, const ushort* __restrict__ Kt,
    const ushort* __restrict__ Vt, const int* __restrict__ adj,
    const float* __restrict__ edge, const float* __restrict__ We,
    const float* __restrict__ Wo, const float* __restrict__ bo,
    float* __restrict__ out) {
  __shared__ __align__(16) char smem[3 * BUFB];

  const int tid = threadIdx.x;
  const int l = tid & 63, h = tid >> 6;
  const int lm = l & 15, g = l >> 4;
  const int b = blockIdx.x >> 6;
  const int m0 = (blockIdx.x & 63) * 16;

  const float Weh = We[h] * LOG2E;
  // B-frag of S^T = K.Q^T : lane holds Q[m0+lm][k=4g+j] (0.25*log2e folded)
  const bf16x4 qf = *(const bf16x4*)(Qs + ((size_t)b * 1024 + m0 + lm) * 128 + h * 16 + g * 4);

  // DMA sources (r9-verified swizzles)
  const ushort* kt0 = Kt + ((size_t)b * 8 + h) * 16384 + l * 8;      // + T*1024
  const int dv = l >> 3, mv = l & 7;                                  // V swizzle
  const int voff = dv * 64 + (((mv * 2) ^ (dv & 6)) * 4);             // elements
  const ushort* vt0 = Vt + ((size_t)b * 8 + h) * 16384 + voff;       // + T*1024
  const int hh = h & 3;
  const int sr = hh * 4 + (l >> 4);                                   // tile row
  const int sci = ((l & 15) * 4) ^ ((sr & 7) << 3);                   // swz col (ints)
  const int* ssrc = ((h < 4) ? adj : (const int*)edge)
                    + (size_t)b * 1048576 + (size_t)(m0 + sr) * 1024 + sci;  // + T*64

  // DMA dests (wave-uniform)
  char* kdst = smem + h * 2048;
  char* vdst = smem + 16384 + h * 2048;
  char* sdst = smem + ((h < 4) ? 32768 : 36864) + hh * 1024;

  float lsum = 0.f;
  f32x4 oacc = {0.f, 0.f, 0.f, 0.f};
  const f32x4 cinit = {-SMAX, -SMAX, -SMAX, -SMAX};

  auto stage = [&](int T, int bi) {
    const int bo_ = bi * BUFB;
    const ushort* ks = kt0 + (size_t)T * 1024;
    const ushort* vs = vt0 + (size_t)T * 1024;
    dma16(ks,        kdst + bo_);
    dma16(ks + 512,  kdst + bo_ + 1024);
    dma16(vs,        vdst + bo_);
    dma16(vs + 512,  vdst + bo_ + 1024);
    dma16(ssrc + T * 64, sdst + bo_);
  };

  auto compute = [&](int bi) {
    const char* base = smem + bi * BUFB;
    const char* kls = base + h * 2048;
    const char* vls = base + 16384 + h * 2048;
    const int* als = (const int*)(base + 32768);
    const int* els = (const int*)(base + 36864);
    const int xorv = (lm & 7) << 3;   // r9-exact: matches sci's ((sr&7)<<3)

    f32x4 st[4];
    bf16x4 vfr[4];
#pragma unroll
    for (int t = 0; t < 4; ++t) {
      // K[n0+16t+lm][4g+j] : element (16t+lm)*16 + 4g
      bf16x4 kf = *(const bf16x4*)(kls + (t * 16 + lm) * 32 + g * 8);
      st[t] = mfma16(kf, qf, cinit);
      // V^T[d=lm][n=16t+4g+j] : granule q=4t+g stored at q^(lm&6)
      vfr[t] = *(const bf16x4*)(vls + lm * 128 + (((t * 4 + g) ^ (lm & 6)) * 8));
    }
#pragma unroll
    for (int t = 0; t < 4; ++t) {
      const int ci = (t * 16 + g * 4) ^ xorv;   // r9-exact int offset
      const i32x4 a4 = *(const i32x4*)(als + lm * 64 + ci);
      const i32x4 e4i = *(const i32x4*)(els + lm * 64 + ci);
      const f32x4 e4 = *(const f32x4*)&e4i;
      bf16x4 pf4;
#pragma unroll
      for (int j = 0; j < 4; ++j) {
        float p = __builtin_amdgcn_exp2f(fmaf(e4[j], Weh, st[t][j]));
        p = (a4[j] == 0) ? 0.f : p;
        lsum += p;
        pf4[j] = (short)f2bfu(p);
      }
      // P^T (S^T C/D layout) == B-frag of PV; O^T[d=4g+r][m=lm]
      oacc = mfma16(vfr[t], pf4, oacc);
    }
  };

  // prologue: tiles 0,1 in flight
  stage(0, 0);
  stage(1, 1);

  int cur = 0;
  for (int ct = 0; ct < 15; ++ct) {
    // wait own tile-ct DMAs (5 stay in flight for tile ct+1) then sync waves
    asm volatile("s_waitcnt vmcnt(5)" ::: "memory");
    __builtin_amdgcn_s_barrier();
    __builtin_amdgcn_sched_barrier(0);
    // all waves vacated buffer (cur+2)%3 -> refill it with tile ct+2
    if (ct < 14) stage(ct + 2, cur >= 1 ? cur - 1 : 2);
    compute(cur);
    cur = (cur == 2) ? 0 : cur + 1;
  }
  asm volatile("s_waitcnt vmcnt(0)" ::: "memory");
  __builtin_amdgcn_s_barrier();
  __builtin_amdgcn_sched_barrier(0);
  compute(cur);   // cur == 0: reads buf0

  // ---- epilogue (r10-verified): normalize, AO tile -> LDS, @Wo + bo ----
  lsum += __shfl_xor(lsum, 16, 64);
  lsum += __shfl_xor(lsum, 32, 64);
  const float inv = 1.0f / lsum;

  __syncthreads();               // all waves done reading buf0 (aot aliases it)
  ushort* aot = (ushort*)smem;   // 16 x 132 bf16
  {
    bf16x4 ov;
    ov[0] = (short)f2bfu(oacc[0] * inv);
    ov[1] = (short)f2bfu(oacc[1] * inv);
    ov[2] = (short)f2bfu(oacc[2] * inv);
    ov[3] = (short)f2bfu(oacc[3] * inv);
    *(bf16x4*)(aot + lm * 132 + h * 16 + g * 4) = ov;   // AO[m=lm][h*16+4g+r]
  }
  __syncthreads();

  f32x4 acc = {0.f, 0.f, 0.f, 0.f};
#pragma unroll
  for (int ks = 0; ks < 8; ++ks) {
    bf16x4 a = *(const bf16x4*)(aot + lm * 132 + ks * 16 + g * 4);  // AO[lm][k]
    const float* wp = Wo + (size_t)(ks * 16 + g * 4) * 128 + h * 16 + lm;
    bf16x4 bfr;
    bfr[0] = (short)f2bfu(wp[0]);   bfr[1] = (short)f2bfu(wp[128]);
    bfr[2] = (short)f2bfu(wp[256]); bfr[3] = (short)f2bfu(wp[384]);
    acc = mfma16(a, bfr, acc);
  }
  const float bv = bo[h * 16 + lm];
  float* op = out + ((size_t)b * 1024 + m0 + g * 4) * 128 + h * 16 + lm;
  op[0 * 128] = acc[0] + bv;
  op[1 * 128] = acc[1] + bv;
  op[2 * 128] = acc[2] + bv;
  op[3 * 128] = acc[3] + bv;
}

extern "C" void kernel_launch(void* const* d_in, const int* in_sizes, int n_in,
                              void* d_out, int out_size, void* d_ws, size_t ws_size,
                              hipStream_t stream) {
  const float* x   = (const float*)d_in[0];
  const int*   adj = (const int*)d_in[1];
  const float* ew  = (const float*)d_in[2];
  const float* Wq  = (const float*)d_in[3];
  const float* bq  = (const float*)d_in[4];
  const float* Wk  = (const float*)d_in[5];
  const float* bk  = (const float*)d_in[6];
  const float* Wv  = (const float*)d_in[7];
  const float* bv  = (const float*)d_in[8];
  const float* Wo  = (const float*)d_in[9];
  const float* bo  = (const float*)d_in[10];
  const float* We  = (const float*)d_in[11];
  // be (d_in[12]) dropped: softmax(x + c) == softmax(x)

  const size_t MN = (size_t)8 * 1024 * 128;  // 1M elements
  ushort* Qs = (ushort*)d_ws;
  ushort* Kt = Qs + MN;
  ushort* Vt = Kt + MN;

  gemm_qkv<<<3072, 256, 0, stream>>>(x, Wq, bq, Wk, bk, Wv, bv, Qs, Kt, Vt);
  attn_kernel<<<512, 512, 0, stream>>>(Qs, Kt, Vt, adj, ew, We, Wo, bo, (float*)d_out);
}

// Round 14
// 52.634 us; speedup vs baseline: 1.8953x; 1.1621x over previous
//
#include <hip/hip_runtime.h>
#include <hip/hip_bf16.h>

typedef __attribute__((ext_vector_type(4))) short bf16x4;   // 4 bf16 = 2 VGPR
typedef __attribute__((ext_vector_type(4))) float f32x4;
typedef __attribute__((ext_vector_type(4))) int i32x4;

#define LOG2E 1.4426950408889634f
#define SMAX 8.0f   // fixed softmax shift (log2 domain); exact after normalization

static __device__ inline f32x4 mfma16(bf16x4 a, bf16x4 b, f32x4 c) {
  return __builtin_amdgcn_mfma_f32_16x16x16bf16_1k(a, b, c, 0, 0, 0);
}
static __device__ inline ushort f2bfu(float f) {
  __hip_bfloat16 h = __float2bfloat16(f);
  return *(ushort*)&h;
}
static __device__ __forceinline__ void dma16(const void* g, void* l) {
  __builtin_amdgcn_global_load_lds(
      (const __attribute__((address_space(1))) void*)g,
      (__attribute__((address_space(3))) void*)l, 16, 0, 0);
}

// ---------------------------------------------------------------------------
// Fused QKV projections, one launch (r10-verified). grid 3072 x 256.
// Q: row-major, scaled 0.25*log2e. K: per-head K^T16 Kt[((b8+h)*1024+n)*16+k].
// V: block-transposed Vt[((b8+h)*16+(n>>6))*1024 + d*64 + (n&63)].
// ---------------------------------------------------------------------------
__global__ __launch_bounds__(256) void gemm_qkv(
    const float* __restrict__ x,
    const float* __restrict__ Wq, const float* __restrict__ bq,
    const float* __restrict__ Wk, const float* __restrict__ bk,
    const float* __restrict__ Wv, const float* __restrict__ bv,
    ushort* __restrict__ Qs, ushort* __restrict__ Kt, ushort* __restrict__ Vt) {
  const int which = blockIdx.x >> 10;       // 0=Q 1=K 2=V
  const int bid = blockIdx.x & 1023;
  const int tid = threadIdx.x;
  const int l = tid & 63, w = tid >> 6;
  const int lm = l & 15, g = l >> 4;
  const int tile = bid * 4 + w;             // 0..4095
  const int mt = tile >> 3, nt = tile & 7;  // 512 x 8
  const int row = mt * 16 + lm;
  const int col = nt * 16 + lm;

  const float* W = (which == 0) ? Wq : (which == 1) ? Wk : Wv;
  const float* bias = (which == 0) ? bq : (which == 1) ? bk : bv;

  f32x4 acc = {0.f, 0.f, 0.f, 0.f};
#pragma unroll
  for (int ks = 0; ks < 8; ++ks) {
    f32x4 av = *(const f32x4*)(x + (size_t)row * 128 + ks * 16 + g * 4);
    bf16x4 a;
    a[0] = (short)f2bfu(av[0]); a[1] = (short)f2bfu(av[1]);
    a[2] = (short)f2bfu(av[2]); a[3] = (short)f2bfu(av[3]);
    const float* wp = W + (size_t)(ks * 16 + g * 4) * 128 + col;
    bf16x4 b;
    b[0] = (short)f2bfu(wp[0]);   b[1] = (short)f2bfu(wp[128]);
    b[2] = (short)f2bfu(wp[256]); b[3] = (short)f2bfu(wp[384]);
    acc = mfma16(a, b, acc);
  }
  const float bv_ = bias[col];
  const float alpha = (which == 0) ? 0.25f * LOG2E : 1.0f;
  float v0 = (acc[0] + bv_) * alpha, v1 = (acc[1] + bv_) * alpha;
  float v2 = (acc[2] + bv_) * alpha, v3 = (acc[3] + bv_) * alpha;
  const int mb = mt * 16;

  if (which == 0) {
    Qs[(size_t)(mb + g * 4 + 0) * 128 + col] = f2bfu(v0);
    Qs[(size_t)(mb + g * 4 + 1) * 128 + col] = f2bfu(v1);
    Qs[(size_t)(mb + g * 4 + 2) * 128 + col] = f2bfu(v2);
    Qs[(size_t)(mb + g * 4 + 3) * 128 + col] = f2bfu(v3);
  } else if (which == 1) {
    const size_t kb = ((size_t)((mb >> 10) * 8 + nt) * 1024 + ((mb & 1023) + g * 4));
    Kt[(kb + 0) * 16 + lm] = f2bfu(v0);
    Kt[(kb + 1) * 16 + lm] = f2bfu(v1);
    Kt[(kb + 2) * 16 + lm] = f2bfu(v2);
    Kt[(kb + 3) * 16 + lm] = f2bfu(v3);
  } else {
    const size_t addr = ((size_t)((mb >> 10) * 8 + nt) * 16 + ((mb & 1023) >> 6)) * 1024
                        + (size_t)lm * 64 + (mb & 63) + g * 4;
    bf16x4 vv;
    vv[0] = (short)f2bfu(v0); vv[1] = (short)f2bfu(v1);
    vv[2] = (short)f2bfu(v2); vv[3] = (short)f2bfu(v3);
    *(bf16x4*)(Vt + addr) = vv;
  }
}

// ---------------------------------------------------------------------------
// Fused attention + output projection. SINGLE DELTA vs r13: 2 LDS buffers
// (81920 B total) -> exactly 2 WGs/CU. Schedule per iter:
// vmcnt(5); bar; compute(ct) from buf ct&1; bar; stage(ct+2) into same buf.
// All swizzles/compute identical to r13 (verified).
// ---------------------------------------------------------------------------
#define BUFB 40960  // bytes per LDS buffer: K 16K | V 16K | adj 4K | edge 4K

__global__ __launch_bounds__(512) void attn_kernel(
    const ushort* __restrict__ Qs, const ushort* __restrict__ Kt,
    const ushort* __restrict__ Vt, const int* __restrict__ adj,
    const float* __restrict__ edge, const float* __restrict__ We,
    const float* __restrict__ Wo, const float* __restrict__ bo,
    float* __restrict__ out) {
  __shared__ __align__(16) char smem[2 * BUFB];

  const int tid = threadIdx.x;
  const int l = tid & 63, h = tid >> 6;
  const int lm = l & 15, g = l >> 4;
  const int b = blockIdx.x >> 6;
  const int m0 = (blockIdx.x & 63) * 16;

  const float Weh = We[h] * LOG2E;
  // B-frag of S^T = K.Q^T : lane holds Q[m0+lm][k=4g+j] (0.25*log2e folded)
  const bf16x4 qf = *(const bf16x4*)(Qs + ((size_t)b * 1024 + m0 + lm) * 128 + h * 16 + g * 4);

  // DMA sources (r9/r13-verified swizzles)
  const ushort* kt0 = Kt + ((size_t)b * 8 + h) * 16384 + l * 8;      // + T*1024
  const int dv = l >> 3, mv = l & 7;                                  // V swizzle
  const int voff = dv * 64 + (((mv * 2) ^ (dv & 6)) * 4);             // elements
  const ushort* vt0 = Vt + ((size_t)b * 8 + h) * 16384 + voff;       // + T*1024
  const int hh = h & 3;
  const int sr = hh * 4 + (l >> 4);                                   // tile row
  const int sci = ((l & 15) * 4) ^ ((sr & 7) << 3);                   // swz col (ints)
  const int* ssrc = ((h < 4) ? adj : (const int*)edge)
                    + (size_t)b * 1048576 + (size_t)(m0 + sr) * 1024 + sci;  // + T*64

  // DMA dests (wave-uniform)
  char* kdst = smem + h * 2048;
  char* vdst = smem + 16384 + h * 2048;
  char* sdst = smem + ((h < 4) ? 32768 : 36864) + hh * 1024;

  float lsum = 0.f;
  f32x4 oacc = {0.f, 0.f, 0.f, 0.f};
  const f32x4 cinit = {-SMAX, -SMAX, -SMAX, -SMAX};

  auto stage = [&](int T) {
    const int bo_ = (T & 1) * BUFB;
    const ushort* ks = kt0 + (size_t)T * 1024;
    const ushort* vs = vt0 + (size_t)T * 1024;
    dma16(ks,        kdst + bo_);
    dma16(ks + 512,  kdst + bo_ + 1024);
    dma16(vs,        vdst + bo_);
    dma16(vs + 512,  vdst + bo_ + 1024);
    dma16(ssrc + T * 64, sdst + bo_);
  };

  auto compute = [&](int bi) {
    const char* base = smem + bi * BUFB;
    const char* kls = base + h * 2048;
    const char* vls = base + 16384 + h * 2048;
    const int* als = (const int*)(base + 32768);
    const int* els = (const int*)(base + 36864);
    const int xorv = (lm & 7) << 3;   // matches sci's ((sr&7)<<3)

    f32x4 st[4];
    bf16x4 vfr[4];
#pragma unroll
    for (int t = 0; t < 4; ++t) {
      // K[n0+16t+lm][4g+j] : element (16t+lm)*16 + 4g
      bf16x4 kf = *(const bf16x4*)(kls + (t * 16 + lm) * 32 + g * 8);
      st[t] = mfma16(kf, qf, cinit);
      // V^T[d=lm][n=16t+4g+j] : granule q=4t+g stored at q^(lm&6)
      vfr[t] = *(const bf16x4*)(vls + lm * 128 + (((t * 4 + g) ^ (lm & 6)) * 8));
    }
#pragma unroll
    for (int t = 0; t < 4; ++t) {
      const int ci = (t * 16 + g * 4) ^ xorv;   // r13-exact int offset
      const i32x4 a4 = *(const i32x4*)(als + lm * 64 + ci);
      const i32x4 e4i = *(const i32x4*)(els + lm * 64 + ci);
      const f32x4 e4 = *(const f32x4*)&e4i;
      bf16x4 pf4;
#pragma unroll
      for (int j = 0; j < 4; ++j) {
        float p = __builtin_amdgcn_exp2f(fmaf(e4[j], Weh, st[t][j]));
        p = (a4[j] == 0) ? 0.f : p;
        lsum += p;
        pf4[j] = (short)f2bfu(p);
      }
      // P^T (S^T C/D layout) == B-frag of PV; O^T[d=4g+r][m=lm]
      oacc = mfma16(vfr[t], pf4, oacc);
    }
  };

  // prologue: tiles 0,1 in flight (buf0, buf1)
  stage(0);
  stage(1);

  for (int ct = 0; ct < 15; ++ct) {
    asm volatile("s_waitcnt vmcnt(5)" ::: "memory");   // own tile-ct DMAs landed
    __builtin_amdgcn_s_barrier();
    __builtin_amdgcn_sched_barrier(0);
    compute(ct & 1);
    __builtin_amdgcn_s_barrier();                      // all waves vacated buf
    __builtin_amdgcn_sched_barrier(0);
    if (ct < 14) stage(ct + 2);                        // refill vacated buffer
  }
  asm volatile("s_waitcnt vmcnt(0)" ::: "memory");
  __builtin_amdgcn_s_barrier();
  __builtin_amdgcn_sched_barrier(0);
  compute(1);   // tile 15 in buf1

  // ---- epilogue (r13-verified): normalize, AO tile -> LDS, @Wo + bo ----
  lsum += __shfl_xor(lsum, 16, 64);
  lsum += __shfl_xor(lsum, 32, 64);
  const float inv = 1.0f / lsum;

  __syncthreads();               // all waves done with buffer reads
  ushort* aot = (ushort*)smem;   // 16 x 132 bf16 (buf0 region; tile15 was buf1)
  {
    bf16x4 ov;
    ov[0] = (short)f2bfu(oacc[0] * inv);
    ov[1] = (short)f2bfu(oacc[1] * inv);
    ov[2] = (short)f2bfu(oacc[2] * inv);
    ov[3] = (short)f2bfu(oacc[3] * inv);
    *(bf16x4*)(aot + lm * 132 + h * 16 + g * 4) = ov;   // AO[m=lm][h*16+4g+r]
  }
  __syncthreads();

  f32x4 acc = {0.f, 0.f, 0.f, 0.f};
#pragma unroll
  for (int ks = 0; ks < 8; ++ks) {
    bf16x4 a = *(const bf16x4*)(aot + lm * 132 + ks * 16 + g * 4);  // AO[lm][k]
    const float* wp = Wo + (size_t)(ks * 16 + g * 4) * 128 + h * 16 + lm;
    bf16x4 bfr;
    bfr[0] = (short)f2bfu(wp[0]);   bfr[1] = (short)f2bfu(wp[128]);
    bfr[2] = (short)f2bfu(wp[256]); bfr[3] = (short)f2bfu(wp[384]);
    acc = mfma16(a, bfr, acc);
  }
  const float bv = bo[h * 16 + lm];
  float* op = out + ((size_t)b * 1024 + m0 + g * 4) * 128 + h * 16 + lm;
  op[0 * 128] = acc[0] + bv;
  op[1 * 128] = acc[1] + bv;
  op[2 * 128] = acc[2] + bv;
  op[3 * 128] = acc[3] + bv;
}

extern "C" void kernel_launch(void* const* d_in, const int* in_sizes, int n_in,
                              void* d_out, int out_size, void* d_ws, size_t ws_size,
                              hipStream_t stream) {
  const float* x   = (const float*)d_in[0];
  const int*   adj = (const int*)d_in[1];
  const float* ew  = (const float*)d_in[2];
  const float* Wq  = (const float*)d_in[3];
  const float* bq  = (const float*)d_in[4];
  const float* Wk  = (const float*)d_in[5];
  const float* bk  = (const float*)d_in[6];
  const float* Wv  = (const float*)d_in[7];
  const float* bv  = (const float*)d_in[8];
  const float* Wo  = (const float*)d_in[9];
  const float* bo  = (const float*)d_in[10];
  const float* We  = (const float*)d_in[11];
  // be (d_in[12]) dropped: softmax(x + c) == softmax(x)

  const size_t MN = (size_t)8 * 1024 * 128;  // 1M elements
  ushort* Qs = (ushort*)d_ws;
  ushort* Kt = Qs + MN;
  ushort* Vt = Kt + MN;

  gemm_qkv<<<3072, 256, 0, stream>>>(x, Wq, bq, Wk, bk, Wv, bv, Qs, Kt, Vt);
  attn_kernel<<<512, 512, 0, stream>>>(Qs, Kt, Vt, adj, ew, We, Wo, bo, (float*)d_out);
}

// Round 15
// 52.437 us; speedup vs baseline: 1.9024x; 1.0038x over previous
//
#include <hip/hip_runtime.h>
#include <hip/hip_bf16.h>

typedef __attribute__((ext_vector_type(4))) short bf16x4;   // 4 bf16 = 2 VGPR
typedef __attribute__((ext_vector_type(4))) float f32x4;
typedef __attribute__((ext_vector_type(4))) int i32x4;

#define LOG2E 1.4426950408889634f
#define SMAX 8.0f   // fixed softmax shift (log2 domain); exact after normalization

static __device__ inline f32x4 mfma16(bf16x4 a, bf16x4 b, f32x4 c) {
  return __builtin_amdgcn_mfma_f32_16x16x16bf16_1k(a, b, c, 0, 0, 0);
}
static __device__ inline ushort f2bfu(float f) {
  __hip_bfloat16 h = __float2bfloat16(f);
  return *(ushort*)&h;
}
static __device__ __forceinline__ void dma16(const void* g, void* l) {
  __builtin_amdgcn_global_load_lds(
      (const __attribute__((address_space(1))) void*)g,
      (__attribute__((address_space(3))) void*)l, 16, 0, 0);
}

// ---------------------------------------------------------------------------
// Fused QKV projections (r10/r14-verified, unchanged). grid 3072 x 256.
// ---------------------------------------------------------------------------
__global__ __launch_bounds__(256) void gemm_qkv(
    const float* __restrict__ x,
    const float* __restrict__ Wq, const float* __restrict__ bq,
    const float* __restrict__ Wk, const float* __restrict__ bk,
    const float* __restrict__ Wv, const float* __restrict__ bv,
    ushort* __restrict__ Qs, ushort* __restrict__ Kt, ushort* __restrict__ Vt) {
  const int which = blockIdx.x >> 10;       // 0=Q 1=K 2=V
  const int bid = blockIdx.x & 1023;
  const int tid = threadIdx.x;
  const int l = tid & 63, w = tid >> 6;
  const int lm = l & 15, g = l >> 4;
  const int tile = bid * 4 + w;             // 0..4095
  const int mt = tile >> 3, nt = tile & 7;  // 512 x 8
  const int row = mt * 16 + lm;
  const int col = nt * 16 + lm;

  const float* W = (which == 0) ? Wq : (which == 1) ? Wk : Wv;
  const float* bias = (which == 0) ? bq : (which == 1) ? bk : bv;

  f32x4 acc = {0.f, 0.f, 0.f, 0.f};
#pragma unroll
  for (int ks = 0; ks < 8; ++ks) {
    f32x4 av = *(const f32x4*)(x + (size_t)row * 128 + ks * 16 + g * 4);
    bf16x4 a;
    a[0] = (short)f2bfu(av[0]); a[1] = (short)f2bfu(av[1]);
    a[2] = (short)f2bfu(av[2]); a[3] = (short)f2bfu(av[3]);
    const float* wp = W + (size_t)(ks * 16 + g * 4) * 128 + col;
    bf16x4 b;
    b[0] = (short)f2bfu(wp[0]);   b[1] = (short)f2bfu(wp[128]);
    b[2] = (short)f2bfu(wp[256]); b[3] = (short)f2bfu(wp[384]);
    acc = mfma16(a, b, acc);
  }
  const float bv_ = bias[col];
  const float alpha = (which == 0) ? 0.25f * LOG2E : 1.0f;
  float v0 = (acc[0] + bv_) * alpha, v1 = (acc[1] + bv_) * alpha;
  float v2 = (acc[2] + bv_) * alpha, v3 = (acc[3] + bv_) * alpha;
  const int mb = mt * 16;

  if (which == 0) {
    Qs[(size_t)(mb + g * 4 + 0) * 128 + col] = f2bfu(v0);
    Qs[(size_t)(mb + g * 4 + 1) * 128 + col] = f2bfu(v1);
    Qs[(size_t)(mb + g * 4 + 2) * 128 + col] = f2bfu(v2);
    Qs[(size_t)(mb + g * 4 + 3) * 128 + col] = f2bfu(v3);
  } else if (which == 1) {
    const size_t kb = ((size_t)((mb >> 10) * 8 + nt) * 1024 + ((mb & 1023) + g * 4));
    Kt[(kb + 0) * 16 + lm] = f2bfu(v0);
    Kt[(kb + 1) * 16 + lm] = f2bfu(v1);
    Kt[(kb + 2) * 16 + lm] = f2bfu(v2);
    Kt[(kb + 3) * 16 + lm] = f2bfu(v3);
  } else {
    const size_t addr = ((size_t)((mb >> 10) * 8 + nt) * 16 + ((mb & 1023) >> 6)) * 1024
                        + (size_t)lm * 64 + (mb & 63) + g * 4;
    bf16x4 vv;
    vv[0] = (short)f2bfu(v0); vv[1] = (short)f2bfu(v1);
    vv[2] = (short)f2bfu(v2); vv[3] = (short)f2bfu(v3);
    *(bf16x4*)(Vt + addr) = vv;
  }
}

// ---------------------------------------------------------------------------
// Fused attention + output projection. DELTA vs r14: one WG = (b, 32-row
// group) = 2 m-subtiles; K/V staged ONCE per WG serve both (staging traffic
// -40% globally). 256 WGs; 2 buffers x 48 KB = 96 KB -> 1 WG/CU, 8 waves.
// 6 DMAs/wave/tile uniform (2K + 2V + 2 adj-or-edge) -> counted vmcnt(6).
// Swizzles r13-exact. Epilogue handles 32 rows.
// ---------------------------------------------------------------------------
#define BUFB 49152  // per buffer: K 16K | V 16K | adj 8K | edge 8K

__global__ __launch_bounds__(512) void attn_kernel(
    const ushort* __restrict__ Qs, const ushort* __restrict__ Kt,
    const ushort* __restrict__ Vt, const int* __restrict__ adj,
    const float* __restrict__ edge, const float* __restrict__ We,
    const float* __restrict__ Wo, const float* __restrict__ bo,
    float* __restrict__ out) {
  __shared__ __align__(16) char smem[2 * BUFB];

  const int tid = threadIdx.x;
  const int l = tid & 63, h = tid >> 6;
  const int lm = l & 15, g = l >> 4;
  const int b = blockIdx.x >> 5;          // 8 batches
  const int m0 = (blockIdx.x & 31) * 32;  // 32 row-groups of 32 rows

  const float Weh = We[h] * LOG2E;
  // Q B-frags for both m-subtiles: lane holds Q[m0+16s+lm][k=4g+j]
  bf16x4 qf0 = *(const bf16x4*)(Qs + ((size_t)b * 1024 + m0 + lm) * 128 + h * 16 + g * 4);
  bf16x4 qf1 = *(const bf16x4*)(Qs + ((size_t)b * 1024 + m0 + 16 + lm) * 128 + h * 16 + g * 4);

  // K/V DMA sources (r13-exact per-head patterns)
  const ushort* kt0 = Kt + ((size_t)b * 8 + h) * 16384 + l * 8;      // + T*1024
  const int dv = l >> 3, mv = l & 7;                                  // V swizzle
  const int voff = dv * 64 + (((mv * 2) ^ (dv & 6)) * 4);             // elements
  const ushort* vt0 = Vt + ((size_t)b * 8 + h) * 16384 + voff;       // + T*1024

  // adj/edge staging: waves 0-3 adj, 4-7 edge; each wave 2 DMAs (rows 8hh..8hh+7)
  // DMA d covers rows 4d..4d+3; lane l -> row 4d+(l>>4), granule (l&15)^((row&7)<<1)
  const int hh = h & 3;
  const int d0 = hh * 2, d1 = d0 + 1;
  const int row0 = 4 * d0 + (l >> 4), row1 = 4 * d1 + (l >> 4);
  const int gr0 = (l & 15) ^ ((row0 & 7) << 1);
  const int gr1 = (l & 15) ^ ((row1 & 7) << 1);
  const int* sbase = ((h < 4) ? adj : (const int*)edge)
                     + (size_t)b * 1048576 + (size_t)m0 * 1024;
  const int* ssrc0 = sbase + (size_t)row0 * 1024 + gr0 * 4;   // + T*64
  const int* ssrc1 = sbase + (size_t)row1 * 1024 + gr1 * 4;   // + T*64

  // DMA dests (wave-uniform)
  char* kdst = smem + h * 2048;
  char* vdst = smem + 16384 + h * 2048;
  char* sreg = smem + ((h < 4) ? 32768 : 40960);
  char* sdst0 = sreg + d0 * 1024;
  char* sdst1 = sreg + d1 * 1024;

  float lsum0 = 0.f, lsum1 = 0.f;
  f32x4 oacc0 = {0.f, 0.f, 0.f, 0.f}, oacc1 = {0.f, 0.f, 0.f, 0.f};
  const f32x4 cinit = {-SMAX, -SMAX, -SMAX, -SMAX};

  auto stage = [&](int T) {
    const int bo_ = (T & 1) * BUFB;
    const ushort* ks = kt0 + (size_t)T * 1024;
    const ushort* vs = vt0 + (size_t)T * 1024;
    dma16(ks,        kdst + bo_);
    dma16(ks + 512,  kdst + bo_ + 1024);
    dma16(vs,        vdst + bo_);
    dma16(vs + 512,  vdst + bo_ + 1024);
    dma16(ssrc0 + T * 64, sdst0 + bo_);
    dma16(ssrc1 + T * 64, sdst1 + bo_);
  };

  auto compute = [&](int bi) {
    const char* base = smem + bi * BUFB;
    const char* kls = base + h * 2048;
    const char* vls = base + 16384 + h * 2048;
    const int* als = (const int*)(base + 32768);
    const int* els = (const int*)(base + 40960);
    const int xorv = (lm & 7) << 3;   // matches staging ((row&7)<<1) granule XOR

    bf16x4 kf[4], vfr[4];
#pragma unroll
    for (int t = 0; t < 4; ++t) {
      kf[t]  = *(const bf16x4*)(kls + (t * 16 + lm) * 32 + g * 8);
      vfr[t] = *(const bf16x4*)(vls + lm * 128 + (((t * 4 + g) ^ (lm & 6)) * 8));
    }
#pragma unroll
    for (int s = 0; s < 2; ++s) {
      const bf16x4 qf = s ? qf1 : qf0;
      f32x4 st[4];
#pragma unroll
      for (int t = 0; t < 4; ++t) st[t] = mfma16(kf[t], qf, cinit);
      float lacc = 0.f;
      f32x4 oac = s ? oacc1 : oacc0;
#pragma unroll
      for (int t = 0; t < 4; ++t) {
        const int ci = (t * 16 + g * 4) ^ xorv;
        const int ro = (16 * s + lm) * 64;
        const i32x4 a4 = *(const i32x4*)(als + ro + ci);
        const i32x4 e4i = *(const i32x4*)(els + ro + ci);
        const f32x4 e4 = *(const f32x4*)&e4i;
        bf16x4 pf4;
#pragma unroll
        for (int j = 0; j < 4; ++j) {
          float p = __builtin_amdgcn_exp2f(fmaf(e4[j], Weh, st[t][j]));
          p = (a4[j] == 0) ? 0.f : p;
          lacc += p;
          pf4[j] = (short)f2bfu(p);
        }
        oac = mfma16(vfr[t], pf4, oac);   // O^T[d=4g+r][m=lm], sub s
      }
      if (s) { oacc1 = oac; lsum1 += lacc; } else { oacc0 = oac; lsum0 += lacc; }
    }
  };

  // prologue: tiles 0,1 in flight (buf0, buf1) -> 12 DMAs/wave outstanding
  stage(0);
  stage(1);

  for (int ct = 0; ct < 15; ++ct) {
    asm volatile("s_waitcnt vmcnt(6)" ::: "memory");   // own tile-ct DMAs landed
    __builtin_amdgcn_s_barrier();
    __builtin_amdgcn_sched_barrier(0);
    compute(ct & 1);
    __builtin_amdgcn_s_barrier();                      // all waves vacated buf
    __builtin_amdgcn_sched_barrier(0);
    if (ct < 14) stage(ct + 2);                        // refill vacated buffer
  }
  asm volatile("s_waitcnt vmcnt(0)" ::: "memory");
  __builtin_amdgcn_s_barrier();
  __builtin_amdgcn_sched_barrier(0);
  compute(1);   // tile 15 in buf1

  // ---- epilogue: normalize, AO (32 x 128) -> LDS, out = AO @ Wo + bo ----
  lsum0 += __shfl_xor(lsum0, 16, 64);
  lsum0 += __shfl_xor(lsum0, 32, 64);
  lsum1 += __shfl_xor(lsum1, 16, 64);
  lsum1 += __shfl_xor(lsum1, 32, 64);
  const float inv0 = 1.0f / lsum0, inv1 = 1.0f / lsum1;

  __syncthreads();               // all waves done with buffer reads
  ushort* aot = (ushort*)smem;   // 32 x 132 bf16 (buf0 region; tile15 was buf1)
  {
    bf16x4 ov;
    ov[0] = (short)f2bfu(oacc0[0] * inv0);
    ov[1] = (short)f2bfu(oacc0[1] * inv0);
    ov[2] = (short)f2bfu(oacc0[2] * inv0);
    ov[3] = (short)f2bfu(oacc0[3] * inv0);
    *(bf16x4*)(aot + (lm) * 132 + h * 16 + g * 4) = ov;
    ov[0] = (short)f2bfu(oacc1[0] * inv1);
    ov[1] = (short)f2bfu(oacc1[1] * inv1);
    ov[2] = (short)f2bfu(oacc1[2] * inv1);
    ov[3] = (short)f2bfu(oacc1[3] * inv1);
    *(bf16x4*)(aot + (16 + lm) * 132 + h * 16 + g * 4) = ov;
  }
  __syncthreads();

  f32x4 acc0 = {0.f, 0.f, 0.f, 0.f}, acc1 = {0.f, 0.f, 0.f, 0.f};
#pragma unroll
  for (int ks = 0; ks < 8; ++ks) {
    const float* wp = Wo + (size_t)(ks * 16 + g * 4) * 128 + h * 16 + lm;
    bf16x4 bfr;
    bfr[0] = (short)f2bfu(wp[0]);   bfr[1] = (short)f2bfu(wp[128]);
    bfr[2] = (short)f2bfu(wp[256]); bfr[3] = (short)f2bfu(wp[384]);
    bf16x4 a0 = *(const bf16x4*)(aot + lm * 132 + ks * 16 + g * 4);
    bf16x4 a1 = *(const bf16x4*)(aot + (16 + lm) * 132 + ks * 16 + g * 4);
    acc0 = mfma16(a0, bfr, acc0);
    acc1 = mfma16(a1, bfr, acc1);
  }
  const float bv = bo[h * 16 + lm];
  float* op0 = out + ((size_t)b * 1024 + m0 + g * 4) * 128 + h * 16 + lm;
  float* op1 = op0 + 16 * 128;
  op0[0 * 128] = acc0[0] + bv;
  op0[1 * 128] = acc0[1] + bv;
  op0[2 * 128] = acc0[2] + bv;
  op0[3 * 128] = acc0[3] + bv;
  op1[0 * 128] = acc1[0] + bv;
  op1[1 * 128] = acc1[1] + bv;
  op1[2 * 128] = acc1[2] + bv;
  op1[3 * 128] = acc1[3] + bv;
}

extern "C" void kernel_launch(void* const* d_in, const int* in_sizes, int n_in,
                              void* d_out, int out_size, void* d_ws, size_t ws_size,
                              hipStream_t stream) {
  const float* x   = (const float*)d_in[0];
  const int*   adj = (const int*)d_in[1];
  const float* ew  = (const float*)d_in[2];
  const float* Wq  = (const float*)d_in[3];
  const float* bq  = (const float*)d_in[4];
  const float* Wk  = (const float*)d_in[5];
  const float* bk  = (const float*)d_in[6];
  const float* Wv  = (const float*)d_in[7];
  const float* bv  = (const float*)d_in[8];
  const float* Wo  = (const float*)d_in[9];
  const float* bo  = (const float*)d_in[10];
  const float* We  = (const float*)d_in[11];
  // be (d_in[12]) dropped: softmax(x + c) == softmax(x)

  const size_t MN = (size_t)8 * 1024 * 128;  // 1M elements
  ushort* Qs = (ushort*)d_ws;
  ushort* Kt = Qs + MN;
  ushort* Vt = Kt + MN;

  gemm_qkv<<<3072, 256, 0, stream>>>(x, Wq, bq, Wk, bk, Wv, bv, Qs, Kt, Vt);
  attn_kernel<<<256, 512, 0, stream>>>(Qs, Kt, Vt, adj, ew, We, Wo, bo, (float*)d_out);
}